// Round 1
// baseline (1788.858 us; speedup 1.0000x reference)
//
#include <hip/hip_runtime.h>

#define NN 100000
#define NE 1600000
#define EN (NE + NN)          // edges incl. self-loops
#define FIN 128
#define H1 8
#define C1 16
#define F1 128                // H1*C1
#define NC 64
#define NEG 0.2f

// ---------------- GEMM: H[n, COLS] = X[n, FIN] @ W[FIN, COLS] ----------------
// block = COLS threads, 64 rows per block. X tile staged in LDS, W streamed
// from L2 (tiny: <=64KB). Thread c accumulates 64 rows for column c.
template <int COLS>
__global__ __launch_bounds__(COLS) void gemm_kernel(
    const float* __restrict__ X, const float* __restrict__ W,
    float* __restrict__ Hout, int nrows) {
  constexpr int ROWS = 64;
  __shared__ float4 xs[ROWS][FIN / 4];  // 32 KB
  const int row0 = blockIdx.x * ROWS;
  const int tid = threadIdx.x;
  const int nr = min(ROWS, nrows - row0);

  const float4* Xv = (const float4*)(X + (size_t)row0 * FIN);
  for (int i = tid; i < nr * (FIN / 4); i += COLS) {
    xs[i >> 5][i & 31] = Xv[i];
  }
  __syncthreads();

  float acc[ROWS];
#pragma unroll
  for (int r = 0; r < ROWS; ++r) acc[r] = 0.f;

  for (int k4 = 0; k4 < FIN / 4; ++k4) {
    float w0 = W[(k4 * 4 + 0) * COLS + tid];
    float w1 = W[(k4 * 4 + 1) * COLS + tid];
    float w2 = W[(k4 * 4 + 2) * COLS + tid];
    float w3 = W[(k4 * 4 + 3) * COLS + tid];
#pragma unroll
    for (int r = 0; r < ROWS; ++r) {
      float4 xv = xs[r][k4];  // LDS broadcast
      acc[r] = fmaf(xv.x, w0, acc[r]);
      acc[r] = fmaf(xv.y, w1, acc[r]);
      acc[r] = fmaf(xv.z, w2, acc[r]);
      acc[r] = fmaf(xv.w, w3, acc[r]);
    }
  }
  for (int r = 0; r < nr; ++r) Hout[(size_t)(row0 + r) * COLS + tid] = acc[r];
}

// ------------- layer-1 per-node attention terms: asn/adn [N,8] ---------------
// one wave per node; lane l covers channels 2l, 2l+1; 8-lane groups = 1 head.
__global__ void attn1_kernel(const float* __restrict__ h1,
                             const float* __restrict__ a_src,
                             const float* __restrict__ a_dst,
                             float* __restrict__ asn, float* __restrict__ adn) {
  int wid = (blockIdx.x * blockDim.x + threadIdx.x) >> 6;
  int lane = threadIdx.x & 63;
  if (wid >= NN) return;
  float2 h = ((const float2*)(h1 + (size_t)wid * F1))[lane];
  float2 as = ((const float2*)a_src)[lane];
  float2 ad = ((const float2*)a_dst)[lane];
  float s = h.x * as.x + h.y * as.y;
  float d = h.x * ad.x + h.y * ad.y;
  s += __shfl_xor(s, 1); s += __shfl_xor(s, 2); s += __shfl_xor(s, 4);
  d += __shfl_xor(d, 1); d += __shfl_xor(d, 2); d += __shfl_xor(d, 4);
  if ((lane & 7) == 0) {
    asn[wid * 8 + (lane >> 3)] = s;
    adn[wid * 8 + (lane >> 3)] = d;
  }
}

// ------------- layer-2 per-node attention terms: asn/adn [N] -----------------
__global__ void attn2_kernel(const float* __restrict__ h2,
                             const float* __restrict__ a_src,
                             const float* __restrict__ a_dst,
                             float* __restrict__ asn, float* __restrict__ adn) {
  int wid = (blockIdx.x * blockDim.x + threadIdx.x) >> 6;
  int lane = threadIdx.x & 63;
  if (wid >= NN) return;
  float h = h2[(size_t)wid * NC + lane];
  float s = h * a_src[lane];
  float d = h * a_dst[lane];
#pragma unroll
  for (int m = 1; m < 64; m <<= 1) { s += __shfl_xor(s, m); d += __shfl_xor(d, m); }
  if (lane == 0) { asn[wid] = s; adn[wid] = d; }
}

// ---------- fused edge pass layer 1: denom += ee; out += ee*h[src] -----------
// 128 threads per edge (one per channel); 2 edges per 256-thread block.
__global__ __launch_bounds__(256) void edge1_kernel(
    const int* __restrict__ srcA, const int* __restrict__ dstA,
    const float* __restrict__ asn, const float* __restrict__ adn,
    const float* __restrict__ h1, float* __restrict__ denom,
    float* __restrict__ outacc) {
  int eg = (blockIdx.x << 1) + (threadIdx.x >> 7);
  if (eg >= EN) return;
  int t = threadIdx.x & 127;
  int s, d;
  if (eg < NE) { s = srcA[eg]; d = dstA[eg]; } else { s = eg - NE; d = s; }
  int h = t >> 4;
  float e = asn[s * 8 + h] + adn[d * 8 + h];
  e = e > 0.f ? e : NEG * e;
  float ee = __expf(e);
  if ((t & 15) == 0) atomicAdd(&denom[d * 8 + h], ee);
  atomicAdd(&outacc[(size_t)d * F1 + t], ee * h1[(size_t)s * F1 + t]);
}

// ---------- fused edge pass layer 2 (1 head, 64 ch): 4 edges / block ---------
__global__ __launch_bounds__(256) void edge2_kernel(
    const int* __restrict__ srcA, const int* __restrict__ dstA,
    const float* __restrict__ asn, const float* __restrict__ adn,
    const float* __restrict__ h2, float* __restrict__ denom,
    float* __restrict__ outacc) {
  int eg = (blockIdx.x << 2) + (threadIdx.x >> 6);
  if (eg >= EN) return;
  int t = threadIdx.x & 63;
  int s, d;
  if (eg < NE) { s = srcA[eg]; d = dstA[eg]; } else { s = eg - NE; d = s; }
  float e = asn[s] + adn[d];
  e = e > 0.f ? e : NEG * e;
  float ee = __expf(e);
  if (t == 0) atomicAdd(&denom[d], ee);
  atomicAdd(&outacc[(size_t)d * NC + t], ee * h2[(size_t)s * NC + t]);
}

// ---------- normalize + bias + elu (in place), feeds layer-2 GEMM ------------
__global__ void elu_norm_kernel(float* __restrict__ buf,
                                const float* __restrict__ denom,
                                const float* __restrict__ b1) {
  int i = blockIdx.x * blockDim.x + threadIdx.x;
  if (i >= NN * F1) return;
  int n = i >> 7, t = i & 127;
  float v = buf[i] / denom[n * 8 + (t >> 4)] + b1[t];
  buf[i] = v > 0.f ? v : __expf(v) - 1.f;
}

// ---------- normalize + bias + log_softmax, one wave per node ----------------
__global__ void final_kernel(const float* __restrict__ out2,
                             const float* __restrict__ denom2,
                             const float* __restrict__ b2,
                             float* __restrict__ out) {
  int wid = (blockIdx.x * blockDim.x + threadIdx.x) >> 6;
  int lane = threadIdx.x & 63;
  if (wid >= NN) return;
  float v = out2[(size_t)wid * NC + lane] / denom2[wid] + b2[lane];
  float m = v;
#pragma unroll
  for (int k = 1; k < 64; k <<= 1) m = fmaxf(m, __shfl_xor(m, k));
  float ex = __expf(v - m);
#pragma unroll
  for (int k = 1; k < 64; k <<= 1) ex += __shfl_xor(ex, k);
  out[(size_t)wid * NC + lane] = v - m - __logf(ex);
}

extern "C" void kernel_launch(void* const* d_in, const int* in_sizes, int n_in,
                              void* d_out, int out_size, void* d_ws,
                              size_t ws_size, hipStream_t stream) {
  const float* x = (const float*)d_in[0];
  const int* edge_index = (const int*)d_in[1];
  const float* W1 = (const float*)d_in[2];
  const float* a_src1 = (const float*)d_in[3];
  const float* a_dst1 = (const float*)d_in[4];
  const float* b1 = (const float*)d_in[5];
  const float* W2 = (const float*)d_in[6];
  const float* a_src2 = (const float*)d_in[7];
  const float* a_dst2 = (const float*)d_in[8];
  const float* b2 = (const float*)d_in[9];
  float* out = (float*)d_out;
  float* ws = (float*)d_ws;

  // workspace layout (floats); regions reused across layers:
  float* h1 = ws;                       // 12.8M  (layer1 h; later layer2 h2)
  float* out1 = ws + 12800000;          // 12.8M  (l1 acc -> x2 -> l2 acc)
  float* asn1 = ws + 25600000;          // 800k
  float* adn1 = asn1 + 800000;          // 800k
  float* denom1 = adn1 + 800000;        // 800k
  float* asn2 = denom1 + 800000;        // 100k
  float* adn2 = asn2 + 100000;          // 100k
  float* denom2 = adn2 + 100000;        // 100k  -> total 28.3M floats = 113MB

  const int* srcA = edge_index;
  const int* dstA = edge_index + NE;

  hipMemsetAsync(denom1, 0, NN * 8 * sizeof(float), stream);
  hipMemsetAsync(out1, 0, (size_t)NN * F1 * sizeof(float), stream);

  gemm_kernel<F1><<<(NN + 63) / 64, F1, 0, stream>>>(x, W1, h1, NN);
  attn1_kernel<<<(NN * 64 + 255) / 256, 256, 0, stream>>>(h1, a_src1, a_dst1,
                                                          asn1, adn1);
  edge1_kernel<<<(EN + 1) / 2, 256, 0, stream>>>(srcA, dstA, asn1, adn1, h1,
                                                 denom1, out1);
  elu_norm_kernel<<<(NN * F1 + 255) / 256, 256, 0, stream>>>(out1, denom1, b1);
  gemm_kernel<NC><<<(NN + 63) / 64, NC, 0, stream>>>(out1, W2, h1, NN);
  attn2_kernel<<<(NN * 64 + 255) / 256, 256, 0, stream>>>(h1, a_src2, a_dst2,
                                                          asn2, adn2);

  float* out2 = out1;  // x2 no longer needed after gemm2
  hipMemsetAsync(denom2, 0, NN * sizeof(float), stream);
  hipMemsetAsync(out2, 0, (size_t)NN * NC * sizeof(float), stream);
  edge2_kernel<<<(EN + 3) / 4, 256, 0, stream>>>(srcA, dstA, asn2, adn2, h1,
                                                 denom2, out2);
  final_kernel<<<(NN * 64 + 255) / 256, 256, 0, stream>>>(out2, denom2, b2,
                                                          out);
}

// Round 2
// 812.584 us; speedup vs baseline: 2.2014x; 2.2014x over previous
//
#include <hip/hip_runtime.h>

#define NN 100000
#define NE 1600000
#define EN (NE + NN)          // edges incl. self-loops
#define FIN 128
#define H1 8
#define C1 16
#define F1 128                // H1*C1
#define NC 64
#define NEG 0.2f

// ---------------- GEMM: H[n, COLS] = X[n, FIN] @ W[FIN, COLS] ----------------
template <int COLS>
__global__ __launch_bounds__(COLS) void gemm_kernel(
    const float* __restrict__ X, const float* __restrict__ W,
    float* __restrict__ Hout, int nrows) {
  constexpr int ROWS = 64;
  __shared__ float4 xs[ROWS][FIN / 4];  // 32 KB
  const int row0 = blockIdx.x * ROWS;
  const int tid = threadIdx.x;
  const int nr = min(ROWS, nrows - row0);

  const float4* Xv = (const float4*)(X + (size_t)row0 * FIN);
  for (int i = tid; i < nr * (FIN / 4); i += COLS) {
    xs[i >> 5][i & 31] = Xv[i];
  }
  __syncthreads();

  float acc[ROWS];
#pragma unroll
  for (int r = 0; r < ROWS; ++r) acc[r] = 0.f;

  for (int k4 = 0; k4 < FIN / 4; ++k4) {
    float w0 = W[(k4 * 4 + 0) * COLS + tid];
    float w1 = W[(k4 * 4 + 1) * COLS + tid];
    float w2 = W[(k4 * 4 + 2) * COLS + tid];
    float w3 = W[(k4 * 4 + 3) * COLS + tid];
#pragma unroll
    for (int r = 0; r < ROWS; ++r) {
      float4 xv = xs[r][k4];  // LDS broadcast
      acc[r] = fmaf(xv.x, w0, acc[r]);
      acc[r] = fmaf(xv.y, w1, acc[r]);
      acc[r] = fmaf(xv.z, w2, acc[r]);
      acc[r] = fmaf(xv.w, w3, acc[r]);
    }
  }
  for (int r = 0; r < nr; ++r) Hout[(size_t)(row0 + r) * COLS + tid] = acc[r];
}

// ------------- layer-1 per-node attention terms: asn/adn [N,8] ---------------
__global__ void attn1_kernel(const float* __restrict__ h1,
                             const float* __restrict__ a_src,
                             const float* __restrict__ a_dst,
                             float* __restrict__ asn, float* __restrict__ adn) {
  int wid = (blockIdx.x * blockDim.x + threadIdx.x) >> 6;
  int lane = threadIdx.x & 63;
  if (wid >= NN) return;
  float2 h = ((const float2*)(h1 + (size_t)wid * F1))[lane];
  float2 as = ((const float2*)a_src)[lane];
  float2 ad = ((const float2*)a_dst)[lane];
  float s = h.x * as.x + h.y * as.y;
  float d = h.x * ad.x + h.y * ad.y;
  s += __shfl_xor(s, 1); s += __shfl_xor(s, 2); s += __shfl_xor(s, 4);
  d += __shfl_xor(d, 1); d += __shfl_xor(d, 2); d += __shfl_xor(d, 4);
  if ((lane & 7) == 0) {
    asn[wid * 8 + (lane >> 3)] = s;
    adn[wid * 8 + (lane >> 3)] = d;
  }
}

// ------------- layer-2 per-node attention terms: asn/adn [N] -----------------
__global__ void attn2_kernel(const float* __restrict__ h2,
                             const float* __restrict__ a_src,
                             const float* __restrict__ a_dst,
                             float* __restrict__ asn, float* __restrict__ adn) {
  int wid = (blockIdx.x * blockDim.x + threadIdx.x) >> 6;
  int lane = threadIdx.x & 63;
  if (wid >= NN) return;
  float h = h2[(size_t)wid * NC + lane];
  float s = h * a_src[lane];
  float d = h * a_dst[lane];
#pragma unroll
  for (int m = 1; m < 64; m <<= 1) { s += __shfl_xor(s, m); d += __shfl_xor(d, m); }
  if (lane == 0) { asn[wid] = s; adn[wid] = d; }
}

// --------------------------- CSR build (by dst) ------------------------------
__global__ __launch_bounds__(256) void hist_kernel(const int* __restrict__ dstA,
                                                   int* __restrict__ deg) {
  int e = blockIdx.x * blockDim.x + threadIdx.x;
  if (e < NE) atomicAdd(&deg[dstA[e]], 1);
  else if (e < EN) atomicAdd(&deg[e - NE], 1);  // self-loop
}

__global__ __launch_bounds__(256) void chunk_sum_kernel(const int* __restrict__ deg,
                                                        int* __restrict__ bsum) {
  int b = blockIdx.x, t = threadIdx.x;
  int s = 0;
  for (int j = 0; j < 4; ++j) {
    int i = b * 1024 + t + j * 256;
    if (i < NN) s += deg[i];
  }
  __shared__ int sd[256];
  sd[t] = s; __syncthreads();
  for (int off = 128; off; off >>= 1) {
    if (t < off) sd[t] += sd[t + off];
    __syncthreads();
  }
  if (!t) bsum[b] = sd[0];
}

__global__ void scan_bsum_kernel(const int* __restrict__ bsum,
                                 int* __restrict__ boff, int nb) {
  if (threadIdx.x == 0 && blockIdx.x == 0) {
    int run = 0;
    for (int i = 0; i < nb; ++i) { boff[i] = run; run += bsum[i]; }
  }
}

__global__ __launch_bounds__(256) void scan_chunk_kernel(
    const int* __restrict__ deg, const int* __restrict__ boff,
    int* __restrict__ rp) {
  __shared__ int sdata[2][256];
  int b = blockIdx.x, t = threadIdx.x;
  int base = b * 1024 + t * 4;
  int v[4], sum = 0;
  for (int j = 0; j < 4; ++j) {
    int idx = base + j;
    v[j] = (idx < NN) ? deg[idx] : 0;
    sum += v[j];
  }
  sdata[0][t] = sum; __syncthreads();
  int src = 0;
  for (int off = 1; off < 256; off <<= 1) {
    int val = sdata[src][t];
    if (t >= off) val += sdata[src][t - off];
    sdata[src ^ 1][t] = val; __syncthreads(); src ^= 1;
  }
  int ex = sdata[src][t] - sum + boff[b];
  for (int j = 0; j < 4; ++j) {
    int idx = base + j;
    if (idx < NN) rp[idx] = ex;
    ex += v[j];
  }
  if (b == 0 && t == 0) rp[NN] = EN;
}

__global__ __launch_bounds__(256) void scatter_kernel(
    const int* __restrict__ srcA, const int* __restrict__ dstA,
    int* __restrict__ cursor, int* __restrict__ col) {
  int e = blockIdx.x * blockDim.x + threadIdx.x;
  if (e >= EN) return;
  int s, d;
  if (e < NE) { s = srcA[e]; d = dstA[e]; } else { s = e - NE; d = s; }
  int pos = atomicAdd(&cursor[d], 1);
  col[pos] = s;
}

// ------ layer-1 gather: softmax-weighted sum over in-edges + bias + ELU ------
// one wave per node; lane l covers channels 2l,2l+1; head = lane>>3.
__global__ __launch_bounds__(256) void gather1_kernel(
    const int* __restrict__ rp, const int* __restrict__ col,
    const float* __restrict__ asn, const float* __restrict__ adn,
    const float* __restrict__ h1, const float* __restrict__ b1,
    float* __restrict__ x2) {
  int node = (blockIdx.x << 2) + (threadIdx.x >> 6);
  if (node >= NN) return;
  int lane = threadIdx.x & 63;
  int head = lane >> 3;
  float aD = adn[node * 8 + head];
  int p = rp[node], p1 = rp[node + 1];
  float accx = 0.f, accy = 0.f, den = 0.f;
  for (; p + 1 < p1; p += 2) {
    int s0 = col[p], s1 = col[p + 1];
    float e0 = asn[s0 * 8 + head] + aD;
    float e1 = asn[s1 * 8 + head] + aD;
    float2 hv0 = ((const float2*)(h1 + (size_t)s0 * F1))[lane];
    float2 hv1 = ((const float2*)(h1 + (size_t)s1 * F1))[lane];
    e0 = e0 > 0.f ? e0 : NEG * e0;
    e1 = e1 > 0.f ? e1 : NEG * e1;
    float ee0 = __expf(e0), ee1 = __expf(e1);
    accx += ee0 * hv0.x + ee1 * hv1.x;
    accy += ee0 * hv0.y + ee1 * hv1.y;
    den += ee0 + ee1;
  }
  if (p < p1) {
    int s0 = col[p];
    float e0 = asn[s0 * 8 + head] + aD;
    float2 hv0 = ((const float2*)(h1 + (size_t)s0 * F1))[lane];
    e0 = e0 > 0.f ? e0 : NEG * e0;
    float ee0 = __expf(e0);
    accx += ee0 * hv0.x; accy += ee0 * hv0.y; den += ee0;
  }
  // all 8 lanes of a head hold identical den — no reduce needed.
  float2 bv = ((const float2*)b1)[lane];
  float ox = accx / den + bv.x;
  float oy = accy / den + bv.y;
  ox = ox > 0.f ? ox : __expf(ox) - 1.f;  // ELU
  oy = oy > 0.f ? oy : __expf(oy) - 1.f;
  float2 o = {ox, oy};
  ((float2*)(x2 + (size_t)node * F1))[lane] = o;
}

// ------ layer-2 gather + bias + log_softmax: one wave per node, lane=ch ------
__global__ __launch_bounds__(256) void gather2_kernel(
    const int* __restrict__ rp, const int* __restrict__ col,
    const float* __restrict__ asn, const float* __restrict__ adn,
    const float* __restrict__ h2, const float* __restrict__ b2,
    float* __restrict__ out) {
  int node = (blockIdx.x << 2) + (threadIdx.x >> 6);
  if (node >= NN) return;
  int lane = threadIdx.x & 63;
  float aD = adn[node];
  int p = rp[node], p1 = rp[node + 1];
  float acc = 0.f, den = 0.f;
  for (; p + 1 < p1; p += 2) {
    int s0 = col[p], s1 = col[p + 1];
    float e0 = asn[s0] + aD;
    float e1 = asn[s1] + aD;
    float hv0 = h2[(size_t)s0 * NC + lane];
    float hv1 = h2[(size_t)s1 * NC + lane];
    e0 = e0 > 0.f ? e0 : NEG * e0;
    e1 = e1 > 0.f ? e1 : NEG * e1;
    float ee0 = __expf(e0), ee1 = __expf(e1);
    acc += ee0 * hv0 + ee1 * hv1;
    den += ee0 + ee1;
  }
  if (p < p1) {
    int s0 = col[p];
    float e0 = asn[s0] + aD;
    float hv0 = h2[(size_t)s0 * NC + lane];
    e0 = e0 > 0.f ? e0 : NEG * e0;
    float ee0 = __expf(e0);
    acc += ee0 * hv0; den += ee0;
  }
  float v = acc / den + b2[lane];
  float m = v;
#pragma unroll
  for (int k = 1; k < 64; k <<= 1) m = fmaxf(m, __shfl_xor(m, k));
  float ex = __expf(v - m);
#pragma unroll
  for (int k = 1; k < 64; k <<= 1) ex += __shfl_xor(ex, k);
  out[(size_t)node * NC + lane] = v - m - __logf(ex);
}

extern "C" void kernel_launch(void* const* d_in, const int* in_sizes, int n_in,
                              void* d_out, int out_size, void* d_ws,
                              size_t ws_size, hipStream_t stream) {
  const float* x = (const float*)d_in[0];
  const int* edge_index = (const int*)d_in[1];
  const float* W1 = (const float*)d_in[2];
  const float* a_src1 = (const float*)d_in[3];
  const float* a_dst1 = (const float*)d_in[4];
  const float* b1 = (const float*)d_in[5];
  const float* W2 = (const float*)d_in[6];
  const float* a_src2 = (const float*)d_in[7];
  const float* a_dst2 = (const float*)d_in[8];
  const float* b2 = (const float*)d_in[9];
  float* out = (float*)d_out;
  float* ws = (float*)d_ws;

  // workspace layout:
  float* h1 = ws;                        // 12.8M floats (layer1 h; later h2)
  float* x2 = h1 + 12800000;             // 12.8M (post-ELU layer-1 output)
  float* asn1 = x2 + 12800000;           // 800k
  float* adn1 = asn1 + 800000;           // 800k
  float* asn2 = adn1 + 800000;           // 100k
  float* adn2 = asn2 + 100000;           // 100k
  int* deg = (int*)(adn2 + 100000);      // NN (reused as cursor)
  int* rp = deg + NN;                    // NN+1
  int* col = rp + NN + 1;                // EN
  int* bsum = col + EN;                  // 128
  int* boff = bsum + 128;                // 128
  // total ~117 MB

  const int* srcA = edge_index;
  const int* dstA = edge_index + NE;
  const int NB = (NN + 1023) / 1024;  // 98

  // ---- CSR build ----
  hipMemsetAsync(deg, 0, NN * sizeof(int), stream);
  hist_kernel<<<(EN + 255) / 256, 256, 0, stream>>>(dstA, deg);
  chunk_sum_kernel<<<NB, 256, 0, stream>>>(deg, bsum);
  scan_bsum_kernel<<<1, 64, 0, stream>>>(bsum, boff, NB);
  scan_chunk_kernel<<<NB, 256, 0, stream>>>(deg, boff, rp);
  hipMemcpyAsync(deg, rp, NN * sizeof(int), hipMemcpyDeviceToDevice, stream);
  scatter_kernel<<<(EN + 255) / 256, 256, 0, stream>>>(srcA, dstA, deg, col);

  // ---- layer 1 ----
  gemm_kernel<F1><<<(NN + 63) / 64, F1, 0, stream>>>(x, W1, h1, NN);
  attn1_kernel<<<(NN * 64 + 255) / 256, 256, 0, stream>>>(h1, a_src1, a_dst1,
                                                          asn1, adn1);
  gather1_kernel<<<(NN + 3) / 4, 256, 0, stream>>>(rp, col, asn1, adn1, h1, b1,
                                                   x2);
  // ---- layer 2 ----
  float* h2 = h1;  // h1 dead after gather1
  gemm_kernel<NC><<<(NN + 63) / 64, NC, 0, stream>>>(x2, W2, h2, NN);
  attn2_kernel<<<(NN * 64 + 255) / 256, 256, 0, stream>>>(h2, a_src2, a_dst2,
                                                          asn2, adn2);
  gather2_kernel<<<(NN + 3) / 4, 256, 0, stream>>>(rp, col, asn2, adn2, h2, b2,
                                                   out);
}

// Round 3
// 592.156 us; speedup vs baseline: 3.0209x; 1.3722x over previous
//
#include <hip/hip_runtime.h>

#define NN 100000
#define NE 1600000
#define EN (NE + NN)          // edges incl. self-loops
#define FIN 128
#define H1 8
#define C1 16
#define F1 128                // H1*C1
#define NC 64
#define NEG 0.2f

// --------------- SGEMM: H[n, BN] = X[n, 128] @ W[128, BN] --------------------
// 256 threads; 8x8 micro-tile per thread in 4+4 split layout; X transposed in
// LDS (stride BM+4: 16B-aligned rows, ~2-way write conflicts); W straight.
template <int BM, int BN>
__global__ __launch_bounds__(256) void sgemm_kernel(
    const float* __restrict__ X, const float* __restrict__ W,
    float* __restrict__ Hout, int nrows) {
  constexpr int BK = 32;
  constexpr int K = 128;
  constexpr int LDX = BM + 4;
  constexpr int LDW = BN + 4;
  constexpr int TN = BN / 8;                 // thread-cols
  __shared__ float Xs[BK][LDX];
  __shared__ float Ws[BK][LDW];
  const int tid = threadIdx.x;
  const int tn = tid % TN;
  const int tm = tid / TN;                   // 256/TN thread-rows, 4+4 rows each
  const int row0 = blockIdx.x * BM;

  float acc[8][8];
#pragma unroll
  for (int i = 0; i < 8; ++i)
#pragma unroll
    for (int j = 0; j < 8; ++j) acc[i][j] = 0.f;

  constexpr int XF4 = BM * BK / 4;           // float4s per X tile
  constexpr int WF4 = BK * BN / 4;

  for (int k0 = 0; k0 < K; k0 += BK) {
    if (k0) __syncthreads();
    // ---- X tile: global row-major -> LDS transposed Xs[k][m] ----
#pragma unroll
    for (int r = 0; r < XF4 / 256; ++r) {
      int i = tid + 256 * r;
      int m = i >> 3;                        // BK/4 = 8 float4 per row
      int q = i & 7;
      int mg = row0 + m;
      if (mg >= nrows) mg = nrows - 1;       // clamp (stores guarded later)
      float4 v = *(const float4*)(X + (size_t)mg * K + k0 + q * 4);
      Xs[q * 4 + 0][m] = v.x;
      Xs[q * 4 + 1][m] = v.y;
      Xs[q * 4 + 2][m] = v.z;
      Xs[q * 4 + 3][m] = v.w;
    }
    // ---- W tile: straight copy Ws[k][n] ----
#pragma unroll
    for (int r = 0; r < WF4 / 256; ++r) {
      int i = tid + 256 * r;
      int k = i / (BN / 4);
      int n4 = i % (BN / 4);
      float4 v = *(const float4*)(W + (size_t)(k0 + k) * BN + n4 * 4);
      *(float4*)&Ws[k][n4 * 4] = v;
    }
    __syncthreads();

#pragma unroll 8
    for (int k = 0; k < BK; ++k) {
      float4 a0 = *(const float4*)&Xs[k][tm * 4];
      float4 a1 = *(const float4*)&Xs[k][BM / 2 + tm * 4];
      float4 b0 = *(const float4*)&Ws[k][tn * 4];
      float4 b1 = *(const float4*)&Ws[k][BN / 2 + tn * 4];
      float a[8] = {a0.x, a0.y, a0.z, a0.w, a1.x, a1.y, a1.z, a1.w};
      float b[8] = {b0.x, b0.y, b0.z, b0.w, b1.x, b1.y, b1.z, b1.w};
#pragma unroll
      for (int i = 0; i < 8; ++i)
#pragma unroll
        for (int j = 0; j < 8; ++j) acc[i][j] = fmaf(a[i], b[j], acc[i][j]);
    }
  }

  // ---- epilogue: coalesced float4 stores, rows guarded ----
#pragma unroll
  for (int i = 0; i < 8; ++i) {
    int row = row0 + (i < 4 ? tm * 4 + i : BM / 2 + tm * 4 + (i - 4));
    if (row >= nrows) continue;
    float4 lo = {acc[i][0], acc[i][1], acc[i][2], acc[i][3]};
    float4 hi = {acc[i][4], acc[i][5], acc[i][6], acc[i][7]};
    *(float4*)(Hout + (size_t)row * BN + tn * 4) = lo;
    *(float4*)(Hout + (size_t)row * BN + BN / 2 + tn * 4) = hi;
  }
}

// ------------- layer-1 per-node attention terms: asn/adn [N,8] ---------------
__global__ void attn1_kernel(const float* __restrict__ h1,
                             const float* __restrict__ a_src,
                             const float* __restrict__ a_dst,
                             float* __restrict__ asn, float* __restrict__ adn) {
  int wid = (blockIdx.x * blockDim.x + threadIdx.x) >> 6;
  int lane = threadIdx.x & 63;
  if (wid >= NN) return;
  float2 h = ((const float2*)(h1 + (size_t)wid * F1))[lane];
  float2 as = ((const float2*)a_src)[lane];
  float2 ad = ((const float2*)a_dst)[lane];
  float s = h.x * as.x + h.y * as.y;
  float d = h.x * ad.x + h.y * ad.y;
  s += __shfl_xor(s, 1); s += __shfl_xor(s, 2); s += __shfl_xor(s, 4);
  d += __shfl_xor(d, 1); d += __shfl_xor(d, 2); d += __shfl_xor(d, 4);
  if ((lane & 7) == 0) {
    asn[wid * 8 + (lane >> 3)] = s;
    adn[wid * 8 + (lane >> 3)] = d;
  }
}

// ------------- layer-2 per-node attention terms: asn/adn [N] -----------------
__global__ void attn2_kernel(const float* __restrict__ h2,
                             const float* __restrict__ a_src,
                             const float* __restrict__ a_dst,
                             float* __restrict__ asn, float* __restrict__ adn) {
  int wid = (blockIdx.x * blockDim.x + threadIdx.x) >> 6;
  int lane = threadIdx.x & 63;
  if (wid >= NN) return;
  float h = h2[(size_t)wid * NC + lane];
  float s = h * a_src[lane];
  float d = h * a_dst[lane];
#pragma unroll
  for (int m = 1; m < 64; m <<= 1) { s += __shfl_xor(s, m); d += __shfl_xor(d, m); }
  if (lane == 0) { asn[wid] = s; adn[wid] = d; }
}

// --------------------------- CSR build (by dst) ------------------------------
__global__ __launch_bounds__(256) void hist_kernel(const int* __restrict__ dstA,
                                                   int* __restrict__ deg) {
  int e = blockIdx.x * blockDim.x + threadIdx.x;
  if (e < NE) atomicAdd(&deg[dstA[e]], 1);
  else if (e < EN) atomicAdd(&deg[e - NE], 1);  // self-loop
}

__global__ __launch_bounds__(256) void chunk_sum_kernel(const int* __restrict__ deg,
                                                        int* __restrict__ bsum) {
  int b = blockIdx.x, t = threadIdx.x;
  int s = 0;
  for (int j = 0; j < 4; ++j) {
    int i = b * 1024 + t + j * 256;
    if (i < NN) s += deg[i];
  }
  __shared__ int sd[256];
  sd[t] = s; __syncthreads();
  for (int off = 128; off; off >>= 1) {
    if (t < off) sd[t] += sd[t + off];
    __syncthreads();
  }
  if (!t) bsum[b] = sd[0];
}

__global__ void scan_bsum_kernel(const int* __restrict__ bsum,
                                 int* __restrict__ boff, int nb) {
  if (threadIdx.x == 0 && blockIdx.x == 0) {
    int run = 0;
    for (int i = 0; i < nb; ++i) { boff[i] = run; run += bsum[i]; }
  }
}

__global__ __launch_bounds__(256) void scan_chunk_kernel(
    const int* __restrict__ deg, const int* __restrict__ boff,
    int* __restrict__ rp) {
  __shared__ int sdata[2][256];
  int b = blockIdx.x, t = threadIdx.x;
  int base = b * 1024 + t * 4;
  int v[4], sum = 0;
  for (int j = 0; j < 4; ++j) {
    int idx = base + j;
    v[j] = (idx < NN) ? deg[idx] : 0;
    sum += v[j];
  }
  sdata[0][t] = sum; __syncthreads();
  int src = 0;
  for (int off = 1; off < 256; off <<= 1) {
    int val = sdata[src][t];
    if (t >= off) val += sdata[src][t - off];
    sdata[src ^ 1][t] = val; __syncthreads(); src ^= 1;
  }
  int ex = sdata[src][t] - sum + boff[b];
  for (int j = 0; j < 4; ++j) {
    int idx = base + j;
    if (idx < NN) rp[idx] = ex;
    ex += v[j];
  }
  if (b == 0 && t == 0) rp[NN] = EN;
}

__global__ __launch_bounds__(256) void scatter_kernel(
    const int* __restrict__ srcA, const int* __restrict__ dstA,
    int* __restrict__ cursor, int* __restrict__ col) {
  int e = blockIdx.x * blockDim.x + threadIdx.x;
  if (e >= EN) return;
  int s, d;
  if (e < NE) { s = srcA[e]; d = dstA[e]; } else { s = e - NE; d = s; }
  int pos = atomicAdd(&cursor[d], 1);
  col[pos] = s;
}

// ------ layer-1 gather: softmax-weighted sum over in-edges + bias + ELU ------
__global__ __launch_bounds__(256) void gather1_kernel(
    const int* __restrict__ rp, const int* __restrict__ col,
    const float* __restrict__ asn, const float* __restrict__ adn,
    const float* __restrict__ h1, const float* __restrict__ b1,
    float* __restrict__ x2) {
  int node = (blockIdx.x << 2) + (threadIdx.x >> 6);
  if (node >= NN) return;
  int lane = threadIdx.x & 63;
  int head = lane >> 3;
  float aD = adn[node * 8 + head];
  int p = rp[node], p1 = rp[node + 1];
  float accx = 0.f, accy = 0.f, den = 0.f;
  for (; p + 1 < p1; p += 2) {
    int s0 = col[p], s1 = col[p + 1];
    float e0 = asn[s0 * 8 + head] + aD;
    float e1 = asn[s1 * 8 + head] + aD;
    float2 hv0 = ((const float2*)(h1 + (size_t)s0 * F1))[lane];
    float2 hv1 = ((const float2*)(h1 + (size_t)s1 * F1))[lane];
    e0 = e0 > 0.f ? e0 : NEG * e0;
    e1 = e1 > 0.f ? e1 : NEG * e1;
    float ee0 = __expf(e0), ee1 = __expf(e1);
    accx += ee0 * hv0.x + ee1 * hv1.x;
    accy += ee0 * hv0.y + ee1 * hv1.y;
    den += ee0 + ee1;
  }
  if (p < p1) {
    int s0 = col[p];
    float e0 = asn[s0 * 8 + head] + aD;
    float2 hv0 = ((const float2*)(h1 + (size_t)s0 * F1))[lane];
    e0 = e0 > 0.f ? e0 : NEG * e0;
    float ee0 = __expf(e0);
    accx += ee0 * hv0.x; accy += ee0 * hv0.y; den += ee0;
  }
  float2 bv = ((const float2*)b1)[lane];
  float ox = accx / den + bv.x;
  float oy = accy / den + bv.y;
  ox = ox > 0.f ? ox : __expf(ox) - 1.f;  // ELU
  oy = oy > 0.f ? oy : __expf(oy) - 1.f;
  float2 o = {ox, oy};
  ((float2*)(x2 + (size_t)node * F1))[lane] = o;
}

// ------ layer-2 gather + bias + log_softmax: one wave per node, lane=ch ------
__global__ __launch_bounds__(256) void gather2_kernel(
    const int* __restrict__ rp, const int* __restrict__ col,
    const float* __restrict__ asn, const float* __restrict__ adn,
    const float* __restrict__ h2, const float* __restrict__ b2,
    float* __restrict__ out) {
  int node = (blockIdx.x << 2) + (threadIdx.x >> 6);
  if (node >= NN) return;
  int lane = threadIdx.x & 63;
  float aD = adn[node];
  int p = rp[node], p1 = rp[node + 1];
  float acc = 0.f, den = 0.f;
  for (; p + 1 < p1; p += 2) {
    int s0 = col[p], s1 = col[p + 1];
    float e0 = asn[s0] + aD;
    float e1 = asn[s1] + aD;
    float hv0 = h2[(size_t)s0 * NC + lane];
    float hv1 = h2[(size_t)s1 * NC + lane];
    e0 = e0 > 0.f ? e0 : NEG * e0;
    e1 = e1 > 0.f ? e1 : NEG * e1;
    float ee0 = __expf(e0), ee1 = __expf(e1);
    acc += ee0 * hv0 + ee1 * hv1;
    den += ee0 + ee1;
  }
  if (p < p1) {
    int s0 = col[p];
    float e0 = asn[s0] + aD;
    float hv0 = h2[(size_t)s0 * NC + lane];
    e0 = e0 > 0.f ? e0 : NEG * e0;
    float ee0 = __expf(e0);
    acc += ee0 * hv0; den += ee0;
  }
  float v = acc / den + b2[lane];
  float m = v;
#pragma unroll
  for (int k = 1; k < 64; k <<= 1) m = fmaxf(m, __shfl_xor(m, k));
  float ex = __expf(v - m);
#pragma unroll
  for (int k = 1; k < 64; k <<= 1) ex += __shfl_xor(ex, k);
  out[(size_t)node * NC + lane] = v - m - __logf(ex);
}

extern "C" void kernel_launch(void* const* d_in, const int* in_sizes, int n_in,
                              void* d_out, int out_size, void* d_ws,
                              size_t ws_size, hipStream_t stream) {
  const float* x = (const float*)d_in[0];
  const int* edge_index = (const int*)d_in[1];
  const float* W1 = (const float*)d_in[2];
  const float* a_src1 = (const float*)d_in[3];
  const float* a_dst1 = (const float*)d_in[4];
  const float* b1 = (const float*)d_in[5];
  const float* W2 = (const float*)d_in[6];
  const float* a_src2 = (const float*)d_in[7];
  const float* a_dst2 = (const float*)d_in[8];
  const float* b2 = (const float*)d_in[9];
  float* out = (float*)d_out;
  float* ws = (float*)d_ws;

  // workspace layout:
  float* h1 = ws;                        // 12.8M floats (layer1 h; later h2)
  float* x2 = h1 + 12800000;             // 12.8M (post-ELU layer-1 output)
  float* asn1 = x2 + 12800000;           // 800k
  float* adn1 = asn1 + 800000;           // 800k
  float* asn2 = adn1 + 800000;           // 100k
  float* adn2 = asn2 + 100000;           // 100k
  int* deg = (int*)(adn2 + 100000);      // NN (reused as cursor)
  int* rp = deg + NN;                    // NN+1
  int* col = rp + NN + 1;                // EN
  int* bsum = col + EN;                  // 128
  int* boff = bsum + 128;                // 128

  const int* srcA = edge_index;
  const int* dstA = edge_index + NE;
  const int NB = (NN + 1023) / 1024;  // 98

  // ---- CSR build ----
  hipMemsetAsync(deg, 0, NN * sizeof(int), stream);
  hist_kernel<<<(EN + 255) / 256, 256, 0, stream>>>(dstA, deg);
  chunk_sum_kernel<<<NB, 256, 0, stream>>>(deg, bsum);
  scan_bsum_kernel<<<1, 64, 0, stream>>>(bsum, boff, NB);
  scan_chunk_kernel<<<NB, 256, 0, stream>>>(deg, boff, rp);
  hipMemcpyAsync(deg, rp, NN * sizeof(int), hipMemcpyDeviceToDevice, stream);
  scatter_kernel<<<(EN + 255) / 256, 256, 0, stream>>>(srcA, dstA, deg, col);

  // ---- layer 1 ----
  sgemm_kernel<128, F1><<<(NN + 127) / 128, 256, 0, stream>>>(x, W1, h1, NN);
  attn1_kernel<<<(NN * 64 + 255) / 256, 256, 0, stream>>>(h1, a_src1, a_dst1,
                                                          asn1, adn1);
  gather1_kernel<<<(NN + 3) / 4, 256, 0, stream>>>(rp, col, asn1, adn1, h1, b1,
                                                   x2);
  // ---- layer 2 ----
  float* h2 = h1;  // h1 dead after gather1
  sgemm_kernel<256, NC><<<(NN + 255) / 256, 256, 0, stream>>>(x2, W2, h2, NN);
  attn2_kernel<<<(NN * 64 + 255) / 256, 256, 0, stream>>>(h2, a_src2, a_dst2,
                                                          asn2, adn2);
  gather2_kernel<<<(NN + 3) / 4, 256, 0, stream>>>(rp, col, asn2, adn2, h2, b2,
                                                   out);
}

// Round 4
// 499.352 us; speedup vs baseline: 3.5824x; 1.1859x over previous
//
#include <hip/hip_runtime.h>

#define NN 100000
#define NE 1600000
#define EN (NE + NN)          // edges incl. self-loops
#define FIN 128
#define H1 8
#define C1 16
#define F1 128                // H1*C1
#define NC 64
#define NEG 0.2f

typedef unsigned short ushort_t;
typedef unsigned int uint_t;

__device__ __forceinline__ ushort_t f2bf(float f) {
  uint_t u = __builtin_bit_cast(uint_t, f);
  u += 0x7FFF + ((u >> 16) & 1);  // RNE
  return (ushort_t)(u >> 16);
}
__device__ __forceinline__ float bf2f(ushort_t s) {
  uint_t u = (uint_t)s << 16;
  return __builtin_bit_cast(float, u);
}

// --------------- SGEMM: H[n, BN] = X[n, 128] @ W[128, BN], bf16 out ---------
// 256 threads; 8x8 micro-tile per thread in 4+4 split layout; X transposed in
// LDS; W straight. Output stored as bf16 (RNE), fp32 accumulation.
template <int BM, int BN>
__global__ __launch_bounds__(256) void sgemm_bf16out_kernel(
    const float* __restrict__ X, const float* __restrict__ W,
    ushort_t* __restrict__ Hout, int nrows) {
  constexpr int BK = 32;
  constexpr int K = 128;
  constexpr int LDX = BM + 4;
  constexpr int LDW = BN + 4;
  constexpr int TN = BN / 8;                 // thread-cols
  __shared__ float Xs[BK][LDX];
  __shared__ float Ws[BK][LDW];
  const int tid = threadIdx.x;
  const int tn = tid % TN;
  const int tm = tid / TN;
  const int row0 = blockIdx.x * BM;

  float acc[8][8];
#pragma unroll
  for (int i = 0; i < 8; ++i)
#pragma unroll
    for (int j = 0; j < 8; ++j) acc[i][j] = 0.f;

  constexpr int XF4 = BM * BK / 4;
  constexpr int WF4 = BK * BN / 4;

  for (int k0 = 0; k0 < K; k0 += BK) {
    if (k0) __syncthreads();
#pragma unroll
    for (int r = 0; r < XF4 / 256; ++r) {
      int i = tid + 256 * r;
      int m = i >> 3;
      int q = i & 7;
      int mg = row0 + m;
      if (mg >= nrows) mg = nrows - 1;
      float4 v = *(const float4*)(X + (size_t)mg * K + k0 + q * 4);
      Xs[q * 4 + 0][m] = v.x;
      Xs[q * 4 + 1][m] = v.y;
      Xs[q * 4 + 2][m] = v.z;
      Xs[q * 4 + 3][m] = v.w;
    }
#pragma unroll
    for (int r = 0; r < WF4 / 256; ++r) {
      int i = tid + 256 * r;
      int k = i / (BN / 4);
      int n4 = i % (BN / 4);
      float4 v = *(const float4*)(W + (size_t)(k0 + k) * BN + n4 * 4);
      *(float4*)&Ws[k][n4 * 4] = v;
    }
    __syncthreads();

#pragma unroll 8
    for (int k = 0; k < BK; ++k) {
      float4 a0 = *(const float4*)&Xs[k][tm * 4];
      float4 a1 = *(const float4*)&Xs[k][BM / 2 + tm * 4];
      float4 b0 = *(const float4*)&Ws[k][tn * 4];
      float4 b1 = *(const float4*)&Ws[k][BN / 2 + tn * 4];
      float a[8] = {a0.x, a0.y, a0.z, a0.w, a1.x, a1.y, a1.z, a1.w};
      float b[8] = {b0.x, b0.y, b0.z, b0.w, b1.x, b1.y, b1.z, b1.w};
#pragma unroll
      for (int i = 0; i < 8; ++i)
#pragma unroll
        for (int j = 0; j < 8; ++j) acc[i][j] = fmaf(a[i], b[j], acc[i][j]);
    }
  }

#pragma unroll
  for (int i = 0; i < 8; ++i) {
    int row = row0 + (i < 4 ? tm * 4 + i : BM / 2 + tm * 4 + (i - 4));
    if (row >= nrows) continue;
    ushort_t lo[4] = {f2bf(acc[i][0]), f2bf(acc[i][1]), f2bf(acc[i][2]),
                      f2bf(acc[i][3])};
    ushort_t hi[4] = {f2bf(acc[i][4]), f2bf(acc[i][5]), f2bf(acc[i][6]),
                      f2bf(acc[i][7])};
    *(uint2*)(Hout + (size_t)row * BN + tn * 4) = *(const uint2*)lo;
    *(uint2*)(Hout + (size_t)row * BN + BN / 2 + tn * 4) = *(const uint2*)hi;
  }
}

// ------------- layer-1 per-node attention terms: asn/adn [N,8] ---------------
__global__ void attn1_kernel(const ushort_t* __restrict__ h1,
                             const float* __restrict__ a_src,
                             const float* __restrict__ a_dst,
                             float* __restrict__ asn, float* __restrict__ adn) {
  int wid = (blockIdx.x * blockDim.x + threadIdx.x) >> 6;
  int lane = threadIdx.x & 63;
  if (wid >= NN) return;
  uint_t hv = ((const uint_t*)(h1 + (size_t)wid * F1))[lane];
  float hx = bf2f((ushort_t)(hv & 0xFFFF));
  float hy = bf2f((ushort_t)(hv >> 16));
  float2 as = ((const float2*)a_src)[lane];
  float2 ad = ((const float2*)a_dst)[lane];
  float s = hx * as.x + hy * as.y;
  float d = hx * ad.x + hy * ad.y;
  s += __shfl_xor(s, 1); s += __shfl_xor(s, 2); s += __shfl_xor(s, 4);
  d += __shfl_xor(d, 1); d += __shfl_xor(d, 2); d += __shfl_xor(d, 4);
  if ((lane & 7) == 0) {
    asn[wid * 8 + (lane >> 3)] = s;
    adn[wid * 8 + (lane >> 3)] = d;
  }
}

// ------------- layer-2 per-node attention terms: asn/adn [N] -----------------
__global__ void attn2_kernel(const ushort_t* __restrict__ h2,
                             const float* __restrict__ a_src,
                             const float* __restrict__ a_dst,
                             float* __restrict__ asn, float* __restrict__ adn) {
  int wid = (blockIdx.x * blockDim.x + threadIdx.x) >> 6;
  int lane = threadIdx.x & 63;
  if (wid >= NN) return;
  float h = bf2f(h2[(size_t)wid * NC + lane]);
  float s = h * a_src[lane];
  float d = h * a_dst[lane];
#pragma unroll
  for (int m = 1; m < 64; m <<= 1) { s += __shfl_xor(s, m); d += __shfl_xor(d, m); }
  if (lane == 0) { asn[wid] = s; adn[wid] = d; }
}

// --------------------------- CSR build (by dst) ------------------------------
__global__ __launch_bounds__(256) void hist_kernel(const int* __restrict__ dstA,
                                                   int* __restrict__ deg) {
  int e = blockIdx.x * blockDim.x + threadIdx.x;
  if (e < NE) atomicAdd(&deg[dstA[e]], 1);
  else if (e < EN) atomicAdd(&deg[e - NE], 1);  // self-loop
}

__global__ __launch_bounds__(256) void chunk_sum_kernel(const int* __restrict__ deg,
                                                        int* __restrict__ bsum) {
  int b = blockIdx.x, t = threadIdx.x;
  int s = 0;
  for (int j = 0; j < 4; ++j) {
    int i = b * 1024 + t + j * 256;
    if (i < NN) s += deg[i];
  }
  __shared__ int sd[256];
  sd[t] = s; __syncthreads();
  for (int off = 128; off; off >>= 1) {
    if (t < off) sd[t] += sd[t + off];
    __syncthreads();
  }
  if (!t) bsum[b] = sd[0];
}

__global__ void scan_bsum_kernel(const int* __restrict__ bsum,
                                 int* __restrict__ boff, int nb) {
  if (threadIdx.x == 0 && blockIdx.x == 0) {
    int run = 0;
    for (int i = 0; i < nb; ++i) { boff[i] = run; run += bsum[i]; }
  }
}

__global__ __launch_bounds__(256) void scan_chunk_kernel(
    const int* __restrict__ deg, const int* __restrict__ boff,
    int* __restrict__ rp) {
  __shared__ int sdata[2][256];
  int b = blockIdx.x, t = threadIdx.x;
  int base = b * 1024 + t * 4;
  int v[4], sum = 0;
  for (int j = 0; j < 4; ++j) {
    int idx = base + j;
    v[j] = (idx < NN) ? deg[idx] : 0;
    sum += v[j];
  }
  sdata[0][t] = sum; __syncthreads();
  int src = 0;
  for (int off = 1; off < 256; off <<= 1) {
    int val = sdata[src][t];
    if (t >= off) val += sdata[src][t - off];
    sdata[src ^ 1][t] = val; __syncthreads(); src ^= 1;
  }
  int ex = sdata[src][t] - sum + boff[b];
  for (int j = 0; j < 4; ++j) {
    int idx = base + j;
    if (idx < NN) rp[idx] = ex;
    ex += v[j];
  }
  if (b == 0 && t == 0) rp[NN] = EN;
}

__global__ __launch_bounds__(256) void scatter_kernel(
    const int* __restrict__ srcA, const int* __restrict__ dstA,
    int* __restrict__ cursor, int* __restrict__ col) {
  int e = blockIdx.x * blockDim.x + threadIdx.x;
  if (e >= EN) return;
  int s, d;
  if (e < NE) { s = srcA[e]; d = dstA[e]; } else { s = e - NE; d = s; }
  int pos = atomicAdd(&cursor[d], 1);
  col[pos] = s;
}

// ------ layer-1 gather: softmax-weighted sum over in-edges + bias + ELU ------
// one wave per node; lane l covers channels 2l,2l+1; head = lane>>3.
__global__ __launch_bounds__(256) void gather1_kernel(
    const int* __restrict__ rp, const int* __restrict__ col,
    const float* __restrict__ asn, const float* __restrict__ adn,
    const ushort_t* __restrict__ h1, const float* __restrict__ b1,
    float* __restrict__ x2) {
  int node = (blockIdx.x << 2) + (threadIdx.x >> 6);
  if (node >= NN) return;
  int lane = threadIdx.x & 63;
  int head = lane >> 3;
  float aD = adn[node * 8 + head];
  int p = rp[node], p1 = rp[node + 1];
  float accx = 0.f, accy = 0.f, den = 0.f;

  for (; p + 3 < p1; p += 4) {
    int s0 = col[p], s1 = col[p + 1], s2 = col[p + 2], s3 = col[p + 3];
    float e0 = asn[s0 * 8 + head] + aD;
    float e1 = asn[s1 * 8 + head] + aD;
    float e2 = asn[s2 * 8 + head] + aD;
    float e3 = asn[s3 * 8 + head] + aD;
    uint_t v0 = ((const uint_t*)(h1 + (size_t)s0 * F1))[lane];
    uint_t v1 = ((const uint_t*)(h1 + (size_t)s1 * F1))[lane];
    uint_t v2 = ((const uint_t*)(h1 + (size_t)s2 * F1))[lane];
    uint_t v3 = ((const uint_t*)(h1 + (size_t)s3 * F1))[lane];
    e0 = e0 > 0.f ? e0 : NEG * e0;
    e1 = e1 > 0.f ? e1 : NEG * e1;
    e2 = e2 > 0.f ? e2 : NEG * e2;
    e3 = e3 > 0.f ? e3 : NEG * e3;
    float ee0 = __expf(e0), ee1 = __expf(e1), ee2 = __expf(e2), ee3 = __expf(e3);
    accx += ee0 * bf2f((ushort_t)(v0 & 0xFFFF)) + ee1 * bf2f((ushort_t)(v1 & 0xFFFF))
          + ee2 * bf2f((ushort_t)(v2 & 0xFFFF)) + ee3 * bf2f((ushort_t)(v3 & 0xFFFF));
    accy += ee0 * bf2f((ushort_t)(v0 >> 16)) + ee1 * bf2f((ushort_t)(v1 >> 16))
          + ee2 * bf2f((ushort_t)(v2 >> 16)) + ee3 * bf2f((ushort_t)(v3 >> 16));
    den += (ee0 + ee1) + (ee2 + ee3);
  }
  for (; p < p1; ++p) {
    int s0 = col[p];
    float e0 = asn[s0 * 8 + head] + aD;
    uint_t v0 = ((const uint_t*)(h1 + (size_t)s0 * F1))[lane];
    e0 = e0 > 0.f ? e0 : NEG * e0;
    float ee0 = __expf(e0);
    accx += ee0 * bf2f((ushort_t)(v0 & 0xFFFF));
    accy += ee0 * bf2f((ushort_t)(v0 >> 16));
    den += ee0;
  }
  float2 bv = ((const float2*)b1)[lane];
  float ox = accx / den + bv.x;
  float oy = accy / den + bv.y;
  ox = ox > 0.f ? ox : __expf(ox) - 1.f;  // ELU
  oy = oy > 0.f ? oy : __expf(oy) - 1.f;
  float2 o = {ox, oy};
  ((float2*)(x2 + (size_t)node * F1))[lane] = o;
}

// ------ layer-2 gather + bias + log_softmax: one wave per node, lane=ch ------
__global__ __launch_bounds__(256) void gather2_kernel(
    const int* __restrict__ rp, const int* __restrict__ col,
    const float* __restrict__ asn, const float* __restrict__ adn,
    const ushort_t* __restrict__ h2, const float* __restrict__ b2,
    float* __restrict__ out) {
  int node = (blockIdx.x << 2) + (threadIdx.x >> 6);
  if (node >= NN) return;
  int lane = threadIdx.x & 63;
  float aD = adn[node];
  int p = rp[node], p1 = rp[node + 1];
  float acc = 0.f, den = 0.f;
  for (; p + 3 < p1; p += 4) {
    int s0 = col[p], s1 = col[p + 1], s2 = col[p + 2], s3 = col[p + 3];
    float e0 = asn[s0] + aD;
    float e1 = asn[s1] + aD;
    float e2 = asn[s2] + aD;
    float e3 = asn[s3] + aD;
    float hv0 = bf2f(h2[(size_t)s0 * NC + lane]);
    float hv1 = bf2f(h2[(size_t)s1 * NC + lane]);
    float hv2 = bf2f(h2[(size_t)s2 * NC + lane]);
    float hv3 = bf2f(h2[(size_t)s3 * NC + lane]);
    e0 = e0 > 0.f ? e0 : NEG * e0;
    e1 = e1 > 0.f ? e1 : NEG * e1;
    e2 = e2 > 0.f ? e2 : NEG * e2;
    e3 = e3 > 0.f ? e3 : NEG * e3;
    float ee0 = __expf(e0), ee1 = __expf(e1), ee2 = __expf(e2), ee3 = __expf(e3);
    acc += ee0 * hv0 + ee1 * hv1 + ee2 * hv2 + ee3 * hv3;
    den += (ee0 + ee1) + (ee2 + ee3);
  }
  for (; p < p1; ++p) {
    int s0 = col[p];
    float e0 = asn[s0] + aD;
    float hv0 = bf2f(h2[(size_t)s0 * NC + lane]);
    e0 = e0 > 0.f ? e0 : NEG * e0;
    float ee0 = __expf(e0);
    acc += ee0 * hv0; den += ee0;
  }
  float v = acc / den + b2[lane];
  float m = v;
#pragma unroll
  for (int k = 1; k < 64; k <<= 1) m = fmaxf(m, __shfl_xor(m, k));
  float ex = __expf(v - m);
#pragma unroll
  for (int k = 1; k < 64; k <<= 1) ex += __shfl_xor(ex, k);
  out[(size_t)node * NC + lane] = v - m - __logf(ex);
}

extern "C" void kernel_launch(void* const* d_in, const int* in_sizes, int n_in,
                              void* d_out, int out_size, void* d_ws,
                              size_t ws_size, hipStream_t stream) {
  const float* x = (const float*)d_in[0];
  const int* edge_index = (const int*)d_in[1];
  const float* W1 = (const float*)d_in[2];
  const float* a_src1 = (const float*)d_in[3];
  const float* a_dst1 = (const float*)d_in[4];
  const float* b1 = (const float*)d_in[5];
  const float* W2 = (const float*)d_in[6];
  const float* a_src2 = (const float*)d_in[7];
  const float* a_dst2 = (const float*)d_in[8];
  const float* b2 = (const float*)d_in[9];
  float* out = (float*)d_out;
  float* ws = (float*)d_ws;

  // workspace layout (in floats):
  ushort_t* h1b = (ushort_t*)ws;         // 12.8M bf16 = 6.4M floats (h1 / h2)
  float* x2 = ws + 6400000;              // 12.8M floats (post-ELU l1 output)
  float* asn1 = x2 + 12800000;           // 800k
  float* adn1 = asn1 + 800000;           // 800k
  float* asn2 = adn1 + 800000;           // 100k
  float* adn2 = asn2 + 100000;           // 100k
  int* deg = (int*)(adn2 + 100000);      // NN (reused as cursor)
  int* rp = deg + NN;                    // NN+1
  int* col = rp + NN + 1;                // EN
  int* bsum = col + EN;                  // 128
  int* boff = bsum + 128;                // 128

  const int* srcA = edge_index;
  const int* dstA = edge_index + NE;
  const int NB = (NN + 1023) / 1024;  // 98

  // ---- CSR build ----
  hipMemsetAsync(deg, 0, NN * sizeof(int), stream);
  hist_kernel<<<(EN + 255) / 256, 256, 0, stream>>>(dstA, deg);
  chunk_sum_kernel<<<NB, 256, 0, stream>>>(deg, bsum);
  scan_bsum_kernel<<<1, 64, 0, stream>>>(bsum, boff, NB);
  scan_chunk_kernel<<<NB, 256, 0, stream>>>(deg, boff, rp);
  hipMemcpyAsync(deg, rp, NN * sizeof(int), hipMemcpyDeviceToDevice, stream);
  scatter_kernel<<<(EN + 255) / 256, 256, 0, stream>>>(srcA, dstA, deg, col);

  // ---- layer 1 ----
  sgemm_bf16out_kernel<128, F1><<<(NN + 127) / 128, 256, 0, stream>>>(x, W1,
                                                                      h1b, NN);
  attn1_kernel<<<(NN * 64 + 255) / 256, 256, 0, stream>>>(h1b, a_src1, a_dst1,
                                                          asn1, adn1);
  gather1_kernel<<<(NN + 3) / 4, 256, 0, stream>>>(rp, col, asn1, adn1, h1b,
                                                   b1, x2);
  // ---- layer 2 ----
  ushort_t* h2b = h1b;  // h1 dead after gather1
  sgemm_bf16out_kernel<256, NC><<<(NN + 255) / 256, 256, 0, stream>>>(x2, W2,
                                                                      h2b, NN);
  attn2_kernel<<<(NN * 64 + 255) / 256, 256, 0, stream>>>(h2b, a_src2, a_dst2,
                                                          asn2, adn2);
  gather2_kernel<<<(NN + 3) / 4, 256, 0, stream>>>(rp, col, asn2, adn2, h2b,
                                                   b2, out);
}

// Round 5
// 355.649 us; speedup vs baseline: 5.0298x; 1.4041x over previous
//
#include <hip/hip_runtime.h>

#define NN 100000
#define NE 1600000
#define EN (NE + NN)          // edges incl. self-loops
#define FIN 128
#define H1 8
#define C1 16
#define F1 128                // H1*C1
#define NC 64
#define NEG 0.2f

// ---- CSR-build multisplit parameters ----
#define BSH 9                 // bucket = dst >> BSH
#define BKN 512               // nodes per bucket
#define NBUK ((NN + BKN - 1) / BKN)   // 196
#define NBLK 256              // edge-chunk blocks for P1/P2
#define CHUNK ((EN + NBLK - 1) / NBLK) // 6641

typedef unsigned short ushort_t;
typedef unsigned int uint_t;

__device__ __forceinline__ ushort_t f2bf(float f) {
  uint_t u = __builtin_bit_cast(uint_t, f);
  u += 0x7FFF + ((u >> 16) & 1);  // RNE
  return (ushort_t)(u >> 16);
}
__device__ __forceinline__ float bf2f(ushort_t s) {
  uint_t u = (uint_t)s << 16;
  return __builtin_bit_cast(float, u);
}

// --------------- SGEMM: H[n, BN] = X[n, 128] @ W[128, BN], bf16 out ---------
template <int BM, int BN>
__global__ __launch_bounds__(256) void sgemm_bf16out_kernel(
    const float* __restrict__ X, const float* __restrict__ W,
    ushort_t* __restrict__ Hout, int nrows) {
  constexpr int BK = 32;
  constexpr int K = 128;
  constexpr int LDX = BM + 4;
  constexpr int LDW = BN + 4;
  constexpr int TN = BN / 8;
  __shared__ float Xs[BK][LDX];
  __shared__ float Ws[BK][LDW];
  const int tid = threadIdx.x;
  const int tn = tid % TN;
  const int tm = tid / TN;
  const int row0 = blockIdx.x * BM;

  float acc[8][8];
#pragma unroll
  for (int i = 0; i < 8; ++i)
#pragma unroll
    for (int j = 0; j < 8; ++j) acc[i][j] = 0.f;

  constexpr int XF4 = BM * BK / 4;
  constexpr int WF4 = BK * BN / 4;

  for (int k0 = 0; k0 < K; k0 += BK) {
    if (k0) __syncthreads();
#pragma unroll
    for (int r = 0; r < XF4 / 256; ++r) {
      int i = tid + 256 * r;
      int m = i >> 3;
      int q = i & 7;
      int mg = row0 + m;
      if (mg >= nrows) mg = nrows - 1;
      float4 v = *(const float4*)(X + (size_t)mg * K + k0 + q * 4);
      Xs[q * 4 + 0][m] = v.x;
      Xs[q * 4 + 1][m] = v.y;
      Xs[q * 4 + 2][m] = v.z;
      Xs[q * 4 + 3][m] = v.w;
    }
#pragma unroll
    for (int r = 0; r < WF4 / 256; ++r) {
      int i = tid + 256 * r;
      int k = i / (BN / 4);
      int n4 = i % (BN / 4);
      float4 v = *(const float4*)(W + (size_t)(k0 + k) * BN + n4 * 4);
      *(float4*)&Ws[k][n4 * 4] = v;
    }
    __syncthreads();

#pragma unroll 8
    for (int k = 0; k < BK; ++k) {
      float4 a0 = *(const float4*)&Xs[k][tm * 4];
      float4 a1 = *(const float4*)&Xs[k][BM / 2 + tm * 4];
      float4 b0 = *(const float4*)&Ws[k][tn * 4];
      float4 b1 = *(const float4*)&Ws[k][BN / 2 + tn * 4];
      float a[8] = {a0.x, a0.y, a0.z, a0.w, a1.x, a1.y, a1.z, a1.w};
      float b[8] = {b0.x, b0.y, b0.z, b0.w, b1.x, b1.y, b1.z, b1.w};
#pragma unroll
      for (int i = 0; i < 8; ++i)
#pragma unroll
        for (int j = 0; j < 8; ++j) acc[i][j] = fmaf(a[i], b[j], acc[i][j]);
    }
  }

#pragma unroll
  for (int i = 0; i < 8; ++i) {
    int row = row0 + (i < 4 ? tm * 4 + i : BM / 2 + tm * 4 + (i - 4));
    if (row >= nrows) continue;
    ushort_t lo[4] = {f2bf(acc[i][0]), f2bf(acc[i][1]), f2bf(acc[i][2]),
                      f2bf(acc[i][3])};
    ushort_t hi[4] = {f2bf(acc[i][4]), f2bf(acc[i][5]), f2bf(acc[i][6]),
                      f2bf(acc[i][7])};
    *(uint2*)(Hout + (size_t)row * BN + tn * 4) = *(const uint2*)lo;
    *(uint2*)(Hout + (size_t)row * BN + BN / 2 + tn * 4) = *(const uint2*)hi;
  }
}

// ------------- layer-1 per-node attention terms: asn/adn [N,8] ---------------
__global__ void attn1_kernel(const ushort_t* __restrict__ h1,
                             const float* __restrict__ a_src,
                             const float* __restrict__ a_dst,
                             float* __restrict__ asn, float* __restrict__ adn) {
  int wid = (blockIdx.x * blockDim.x + threadIdx.x) >> 6;
  int lane = threadIdx.x & 63;
  if (wid >= NN) return;
  uint_t hv = ((const uint_t*)(h1 + (size_t)wid * F1))[lane];
  float hx = bf2f((ushort_t)(hv & 0xFFFF));
  float hy = bf2f((ushort_t)(hv >> 16));
  float2 as = ((const float2*)a_src)[lane];
  float2 ad = ((const float2*)a_dst)[lane];
  float s = hx * as.x + hy * as.y;
  float d = hx * ad.x + hy * ad.y;
  s += __shfl_xor(s, 1); s += __shfl_xor(s, 2); s += __shfl_xor(s, 4);
  d += __shfl_xor(d, 1); d += __shfl_xor(d, 2); d += __shfl_xor(d, 4);
  if ((lane & 7) == 0) {
    asn[wid * 8 + (lane >> 3)] = s;
    adn[wid * 8 + (lane >> 3)] = d;
  }
}

// ------------- layer-2 per-node attention terms: asn/adn [N] -----------------
__global__ void attn2_kernel(const ushort_t* __restrict__ h2,
                             const float* __restrict__ a_src,
                             const float* __restrict__ a_dst,
                             float* __restrict__ asn, float* __restrict__ adn) {
  int wid = (blockIdx.x * blockDim.x + threadIdx.x) >> 6;
  int lane = threadIdx.x & 63;
  if (wid >= NN) return;
  float h = bf2f(h2[(size_t)wid * NC + lane]);
  float s = h * a_src[lane];
  float d = h * a_dst[lane];
#pragma unroll
  for (int m = 1; m < 64; m <<= 1) { s += __shfl_xor(s, m); d += __shfl_xor(d, m); }
  if (lane == 0) { asn[wid] = s; adn[wid] = d; }
}

// ------------------ CSR build: two-level multisplit by dst -------------------
// P1: per-(bucket, block) counts. cnt layout: cnt[bucket * NBLK + block].
__global__ __launch_bounds__(512) void bucket_count_kernel(
    const int* __restrict__ dstA, int* __restrict__ cnt) {
  __shared__ int histL[NBUK];
  int b = blockIdx.x, t = threadIdx.x;
  for (int i = t; i < NBUK; i += 512) histL[i] = 0;
  __syncthreads();
  int e0 = b * CHUNK, e1 = min(e0 + CHUNK, EN);
  for (int e = e0 + t; e < e1; e += 512) {
    int d = (e < NE) ? dstA[e] : (e - NE);
    atomicAdd(&histL[d >> BSH], 1);
  }
  __syncthreads();
  for (int i = t; i < NBUK; i += 512) cnt[i * NBLK + b] = histL[i];
}

// scan: cnt -> absolute per-(bucket,block) offsets; bucket_base[NBUK+1].
__global__ __launch_bounds__(256) void bucket_scan_kernel(
    int* __restrict__ cnt, int* __restrict__ bucket_base) {
  __shared__ int colsum[NBUK];
  int t = threadIdx.x;
  if (t < NBUK) {
    int run = 0;
    int* c = cnt + t * NBLK;
    for (int b = 0; b < NBLK; ++b) { int v = c[b]; c[b] = run; run += v; }
    colsum[t] = run;
  }
  __syncthreads();
  if (t == 0) {
    int base = 0;
    for (int j = 0; j < NBUK; ++j) {
      bucket_base[j] = base;
      int v = colsum[j];
      colsum[j] = base;
      base += v;
    }
    bucket_base[NBUK] = base;  // == EN
  }
  __syncthreads();
  if (t < NBUK) {
    int bb = colsum[t];
    int* c = cnt + t * NBLK;
    for (int b = 0; b < NBLK; ++b) c[b] += bb;
  }
}

// P2: scatter edges into bucket-contiguous staging; each block writes NBUK
// private sequential streams. pack = src | (dst & 511) << 17.
__global__ __launch_bounds__(512) void bucket_scatter_kernel(
    const int* __restrict__ srcA, const int* __restrict__ dstA,
    const int* __restrict__ cnt, int* __restrict__ staging) {
  __shared__ int cur[NBUK];
  int b = blockIdx.x, t = threadIdx.x;
  for (int i = t; i < NBUK; i += 512) cur[i] = cnt[i * NBLK + b];
  __syncthreads();
  int e0 = b * CHUNK, e1 = min(e0 + CHUNK, EN);
  for (int e = e0 + t; e < e1; e += 512) {
    int s, d;
    if (e < NE) { s = srcA[e]; d = dstA[e]; } else { s = e - NE; d = s; }
    int pos = atomicAdd(&cur[d >> BSH], 1);
    staging[pos] = s | ((d & (BKN - 1)) << 17);
  }
}

// P3: per-bucket fine CSR in LDS: hist -> scan -> rp -> cursor scatter.
__global__ __launch_bounds__(512) void bucket_csr_kernel(
    const int* __restrict__ staging, const int* __restrict__ bucket_base,
    int* __restrict__ rp, int* __restrict__ col) {
  __shared__ int degL[BKN];
  __shared__ int exclL[BKN];
  __shared__ int sdata[2][BKN];
  int bk = blockIdx.x, t = threadIdx.x;
  int ebase = bucket_base[bk], eend = bucket_base[bk + 1];
  degL[t] = 0;
  __syncthreads();
  for (int e = ebase + t; e < eend; e += 512)
    atomicAdd(&degL[staging[e] >> 17], 1);
  __syncthreads();
  // inclusive block scan of degL (512 values, 1/thread), ping-pong
  int v = degL[t];
  sdata[0][t] = v;
  __syncthreads();
  int sp = 0;
  for (int off = 1; off < BKN; off <<= 1) {
    int val = sdata[sp][t];
    if (t >= off) val += sdata[sp][t - off];
    sdata[sp ^ 1][t] = val;
    __syncthreads();
    sp ^= 1;
  }
  int ex = sdata[sp][t] - v + ebase;  // absolute exclusive offset
  exclL[t] = ex;
  int node = bk * BKN + t;
  if (node < NN) rp[node] = ex;
  if (bk == 0 && t == 0) rp[NN] = EN;
  __syncthreads();
  for (int e = ebase + t; e < eend; e += 512) {
    int pk = staging[e];
    int pos = atomicAdd(&exclL[pk >> 17], 1);
    col[pos] = pk & 0x1FFFF;
  }
}

// ------ layer-1 gather: softmax-weighted sum over in-edges + bias + ELU ------
__global__ __launch_bounds__(256) void gather1_kernel(
    const int* __restrict__ rp, const int* __restrict__ col,
    const float* __restrict__ asn, const float* __restrict__ adn,
    const ushort_t* __restrict__ h1, const float* __restrict__ b1,
    float* __restrict__ x2) {
  int node = (blockIdx.x << 2) + (threadIdx.x >> 6);
  if (node >= NN) return;
  int lane = threadIdx.x & 63;
  int head = lane >> 3;
  float aD = adn[node * 8 + head];
  int p = rp[node], p1 = rp[node + 1];
  float accx = 0.f, accy = 0.f, den = 0.f;

  for (; p + 3 < p1; p += 4) {
    int s0 = col[p], s1 = col[p + 1], s2 = col[p + 2], s3 = col[p + 3];
    float e0 = asn[s0 * 8 + head] + aD;
    float e1 = asn[s1 * 8 + head] + aD;
    float e2 = asn[s2 * 8 + head] + aD;
    float e3 = asn[s3 * 8 + head] + aD;
    uint_t v0 = ((const uint_t*)(h1 + (size_t)s0 * F1))[lane];
    uint_t v1 = ((const uint_t*)(h1 + (size_t)s1 * F1))[lane];
    uint_t v2 = ((const uint_t*)(h1 + (size_t)s2 * F1))[lane];
    uint_t v3 = ((const uint_t*)(h1 + (size_t)s3 * F1))[lane];
    e0 = e0 > 0.f ? e0 : NEG * e0;
    e1 = e1 > 0.f ? e1 : NEG * e1;
    e2 = e2 > 0.f ? e2 : NEG * e2;
    e3 = e3 > 0.f ? e3 : NEG * e3;
    float ee0 = __expf(e0), ee1 = __expf(e1), ee2 = __expf(e2), ee3 = __expf(e3);
    accx += ee0 * bf2f((ushort_t)(v0 & 0xFFFF)) + ee1 * bf2f((ushort_t)(v1 & 0xFFFF))
          + ee2 * bf2f((ushort_t)(v2 & 0xFFFF)) + ee3 * bf2f((ushort_t)(v3 & 0xFFFF));
    accy += ee0 * bf2f((ushort_t)(v0 >> 16)) + ee1 * bf2f((ushort_t)(v1 >> 16))
          + ee2 * bf2f((ushort_t)(v2 >> 16)) + ee3 * bf2f((ushort_t)(v3 >> 16));
    den += (ee0 + ee1) + (ee2 + ee3);
  }
  for (; p < p1; ++p) {
    int s0 = col[p];
    float e0 = asn[s0 * 8 + head] + aD;
    uint_t v0 = ((const uint_t*)(h1 + (size_t)s0 * F1))[lane];
    e0 = e0 > 0.f ? e0 : NEG * e0;
    float ee0 = __expf(e0);
    accx += ee0 * bf2f((ushort_t)(v0 & 0xFFFF));
    accy += ee0 * bf2f((ushort_t)(v0 >> 16));
    den += ee0;
  }
  float2 bv = ((const float2*)b1)[lane];
  float ox = accx / den + bv.x;
  float oy = accy / den + bv.y;
  ox = ox > 0.f ? ox : __expf(ox) - 1.f;  // ELU
  oy = oy > 0.f ? oy : __expf(oy) - 1.f;
  float2 o = {ox, oy};
  ((float2*)(x2 + (size_t)node * F1))[lane] = o;
}

// ------ layer-2 gather + bias + log_softmax: one wave per node, lane=ch ------
__global__ __launch_bounds__(256) void gather2_kernel(
    const int* __restrict__ rp, const int* __restrict__ col,
    const float* __restrict__ asn, const float* __restrict__ adn,
    const ushort_t* __restrict__ h2, const float* __restrict__ b2,
    float* __restrict__ out) {
  int node = (blockIdx.x << 2) + (threadIdx.x >> 6);
  if (node >= NN) return;
  int lane = threadIdx.x & 63;
  float aD = adn[node];
  int p = rp[node], p1 = rp[node + 1];
  float acc = 0.f, den = 0.f;
  for (; p + 3 < p1; p += 4) {
    int s0 = col[p], s1 = col[p + 1], s2 = col[p + 2], s3 = col[p + 3];
    float e0 = asn[s0] + aD;
    float e1 = asn[s1] + aD;
    float e2 = asn[s2] + aD;
    float e3 = asn[s3] + aD;
    float hv0 = bf2f(h2[(size_t)s0 * NC + lane]);
    float hv1 = bf2f(h2[(size_t)s1 * NC + lane]);
    float hv2 = bf2f(h2[(size_t)s2 * NC + lane]);
    float hv3 = bf2f(h2[(size_t)s3 * NC + lane]);
    e0 = e0 > 0.f ? e0 : NEG * e0;
    e1 = e1 > 0.f ? e1 : NEG * e1;
    e2 = e2 > 0.f ? e2 : NEG * e2;
    e3 = e3 > 0.f ? e3 : NEG * e3;
    float ee0 = __expf(e0), ee1 = __expf(e1), ee2 = __expf(e2), ee3 = __expf(e3);
    acc += ee0 * hv0 + ee1 * hv1 + ee2 * hv2 + ee3 * hv3;
    den += (ee0 + ee1) + (ee2 + ee3);
  }
  for (; p < p1; ++p) {
    int s0 = col[p];
    float e0 = asn[s0] + aD;
    float hv0 = bf2f(h2[(size_t)s0 * NC + lane]);
    e0 = e0 > 0.f ? e0 : NEG * e0;
    float ee0 = __expf(e0);
    acc += ee0 * hv0; den += ee0;
  }
  float v = acc / den + b2[lane];
  float m = v;
#pragma unroll
  for (int k = 1; k < 64; k <<= 1) m = fmaxf(m, __shfl_xor(m, k));
  float ex = __expf(v - m);
#pragma unroll
  for (int k = 1; k < 64; k <<= 1) ex += __shfl_xor(ex, k);
  out[(size_t)node * NC + lane] = v - m - __logf(ex);
}

extern "C" void kernel_launch(void* const* d_in, const int* in_sizes, int n_in,
                              void* d_out, int out_size, void* d_ws,
                              size_t ws_size, hipStream_t stream) {
  const float* x = (const float*)d_in[0];
  const int* edge_index = (const int*)d_in[1];
  const float* W1 = (const float*)d_in[2];
  const float* a_src1 = (const float*)d_in[3];
  const float* a_dst1 = (const float*)d_in[4];
  const float* b1 = (const float*)d_in[5];
  const float* W2 = (const float*)d_in[6];
  const float* a_src2 = (const float*)d_in[7];
  const float* a_dst2 = (const float*)d_in[8];
  const float* b2 = (const float*)d_in[9];
  float* out = (float*)d_out;
  float* ws = (float*)d_ws;

  // workspace layout (in floats):
  ushort_t* h1b = (ushort_t*)ws;         // 12.8M bf16 = 6.4M floats (h1 / h2)
  float* x2 = ws + 6400000;              // 12.8M floats (post-ELU l1 output)
  float* asn1 = x2 + 12800000;           // 800k
  float* adn1 = asn1 + 800000;           // 800k
  float* asn2 = adn1 + 800000;           // 100k
  float* adn2 = asn2 + 100000;           // 100k
  int* rp = (int*)(adn2 + 100000);       // NN+1
  int* col = rp + NN + 1;                // EN
  int* staging = col + EN;               // EN
  int* cnt = staging + EN;               // NBUK*NBLK = 50176
  int* bucket_base = cnt + NBUK * NBLK;  // NBUK+1

  const int* srcA = edge_index;
  const int* dstA = edge_index + NE;

  // ---- CSR build (multisplit) ----
  bucket_count_kernel<<<NBLK, 512, 0, stream>>>(dstA, cnt);
  bucket_scan_kernel<<<1, 256, 0, stream>>>(cnt, bucket_base);
  bucket_scatter_kernel<<<NBLK, 512, 0, stream>>>(srcA, dstA, cnt, staging);
  bucket_csr_kernel<<<NBUK, 512, 0, stream>>>(staging, bucket_base, rp, col);

  // ---- layer 1 ----
  sgemm_bf16out_kernel<128, F1><<<(NN + 127) / 128, 256, 0, stream>>>(x, W1,
                                                                      h1b, NN);
  attn1_kernel<<<(NN * 64 + 255) / 256, 256, 0, stream>>>(h1b, a_src1, a_dst1,
                                                          asn1, adn1);
  gather1_kernel<<<(NN + 3) / 4, 256, 0, stream>>>(rp, col, asn1, adn1, h1b,
                                                   b1, x2);
  // ---- layer 2 ----
  ushort_t* h2b = h1b;  // h1 dead after gather1
  sgemm_bf16out_kernel<256, NC><<<(NN + 255) / 256, 256, 0, stream>>>(x2, W2,
                                                                      h2b, NN);
  attn2_kernel<<<(NN * 64 + 255) / 256, 256, 0, stream>>>(h2b, a_src2, a_dst2,
                                                          asn2, adn2);
  gather2_kernel<<<(NN + 3) / 4, 256, 0, stream>>>(rp, col, asn2, adn2, h2b,
                                                   b2, out);
}